// Round 7
// baseline (351.260 us; speedup 1.0000x reference)
//
#include <hip/hip_runtime.h>
#include <math.h>

#define S_LEN 1024
#define BATCH 8
#define NH 8
#define QD 32
#define PD 4
#define EMB 512
#define NPROJ 544
#define LPOS 2047  // 2*S-1

typedef __attribute__((ext_vector_type(8))) short short8;   // 8 bf16 = 4 VGPR
typedef __attribute__((ext_vector_type(4))) float f32x4;
typedef __attribute__((ext_vector_type(4))) unsigned int u32x4;
typedef __attribute__((ext_vector_type(2))) unsigned int u32x2;

union U4 { u32x4 u; short8 s; };

// fp32 -> bf16 round-to-nearest-even
static __device__ inline unsigned short f2bf(float f) {
    unsigned int u = __builtin_bit_cast(unsigned int, f);
    u += 0x7fffu + ((u >> 16) & 1u);
    return (unsigned short)(u >> 16);
}

// ---------------------------------------------------------------------------
// Kernel 0 (merged): blocks [0,2184) convert X/W f32->bf16 (2 f32x4/thread);
//                    blocks [2184,2440) compute PE, store reversed bf16 PAIRS.
// PEp[h][w] (16B) = { PE4r[h][w], PE4r[h][w+1] }, PE4r[h][w][t] =
// bf16(PE[2046-w][h*4+t]). Each value lands in lo-half of slot w and hi-half
// of slot w-1. Slot 2046's hi-half never written/read (attn reads w<=2045).
// ---------------------------------------------------------------------------
#define NXV 1048576   // X float4 count
#define NWV 69632     // W float4 count
#define CONV_BLOCKS 2184
__global__ __launch_bounds__(256) void prep_kernel(
    const float* __restrict__ X, const float* __restrict__ W,
    const float* __restrict__ pos, const float* __restrict__ Wp,
    unsigned short* __restrict__ Xb, unsigned short* __restrict__ Wb,
    unsigned short* __restrict__ PEp)
{
    const int bx = blockIdx.x;
    if (bx < CONV_BLOCKS) {
        int idx = bx * 256 + threadIdx.x;
        int i = idx * 2;   // NXV even: a pair never straddles the X/W boundary
        const f32x4* src;
        unsigned short* dst;
        if (i < NXV)            { src = (const f32x4*)X; dst = Xb; }
        else if (i < NXV + NWV) { src = (const f32x4*)W; dst = Wb; i -= NXV; }
        else return;
        f32x4 v0 = src[i], v1 = src[i + 1];
        union { unsigned short s[8]; u32x4 u; } pk;
        pk.s[0] = f2bf(v0.x); pk.s[1] = f2bf(v0.y);
        pk.s[2] = f2bf(v0.z); pk.s[3] = f2bf(v0.w);
        pk.s[4] = f2bf(v1.x); pk.s[5] = f2bf(v1.y);
        pk.s[6] = f2bf(v1.z); pk.s[7] = f2bf(v1.w);
        ((u32x4*)dst)[i >> 1] = pk.u;
    } else {
        int o = (bx - CONV_BLOCKS) * 256 + threadIdx.x;
        if (o >= LPOS * 32) return;
        int l = o >> 5, ht = o & 31;
        const f32x4* pr = (const f32x4*)(pos + (size_t)l * 192);
        const f32x4* wr = (const f32x4*)(Wp + (size_t)ht * 192);
        float acc = 0.0f;
#pragma unroll 8
        for (int d = 0; d < 48; ++d) {
            f32x4 a = pr[d], w = wr[d];
            acc += a.x * w.x + a.y * w.y + a.z * w.z + a.w * w.w;
        }
        int h = ht >> 2, t = ht & 3, w = 2046 - l;
        unsigned short v = f2bf(acc);
        PEp[((size_t)h * LPOS + w) * 8 + t] = v;
        if (w >= 1)
            PEp[((size_t)h * LPOS + (w - 1)) * 8 + 4 + t] = v;
    }
}

// ---------------------------------------------------------------------------
// Kernel 1: proj^T = W(544x512) @ X^T(512x8192) via MFMA.
// W o-tile staged in LDS (2 k-phases of 256), conflict-free padded rows.
// Block 256 (4 waves): tile 64 o x 128 m; wave wv: 32 m-rows (2 groups of 16),
// 4 o-subtiles -> 8 MFMAs per kk, each LDS aw read feeds 2 MFMAs.
// ---------------------------------------------------------------------------
#define WROW 264   // shorts per LDS W row (256 data + 8 pad): 528 B, 16B-aligned,
                   // row step 132 words -> +4 banks/row -> 2-way on b128 (free)
__global__ __launch_bounds__(256) void proj_kernel(
    const unsigned short* __restrict__ Xb, const unsigned short* __restrict__ Wb,
    const float* __restrict__ bias,
    unsigned short* __restrict__ Qb, unsigned short* __restrict__ Kb,
    unsigned short* __restrict__ Pb)
{
    __shared__ unsigned short wlds[64 * WROW];   // 33,792 B

    const int tid = threadIdx.x;
    const int wv = tid >> 6, lane = tid & 63;
    const int n16 = lane & 15, quad = lane >> 4;
    const int m0 = blockIdx.x * 128, o0 = blockIdx.y * 64;
    const int mrow = m0 + wv * 32 + n16;          // group g adds +16
    const unsigned short* xrow = Xb + (size_t)mrow * EMB;

    f32x4 acc[2][4] = {{{0,0,0,0},{0,0,0,0},{0,0,0,0},{0,0,0,0}},
                       {{0,0,0,0},{0,0,0,0},{0,0,0,0},{0,0,0,0}}};

#pragma unroll
    for (int phase = 0; phase < 2; ++phase) {
        __syncthreads();   // previous phase fully consumed
#pragma unroll
        for (int u = 0; u < 8; ++u) {
            int idx = tid + 256 * u;          // 0..2047
            int r = idx >> 5, c = idx & 31;   // row, 16B chunk within 512B half-row
            int o = o0 + r; if (o > NPROJ - 1) o = NPROJ - 1;
            u32x4 v = *(const u32x4*)(Wb + (size_t)o * EMB + phase * 256 + c * 8);
            *(u32x4*)(wlds + r * WROW + c * 8) = v;
        }
        __syncthreads();
#pragma unroll
        for (int kk = 0; kk < 8; ++kk) {
            const int k0 = kk * 32;
            U4 bx0; bx0.u = *(const u32x4*)(xrow + phase * 256 + k0 + quad * 8);
            U4 bx1; bx1.u = *(const u32x4*)(xrow + (size_t)16 * EMB + phase * 256 + k0 + quad * 8);
#pragma unroll
            for (int ot = 0; ot < 4; ++ot) {
                U4 aw; aw.u = *(const u32x4*)(wlds + (ot * 16 + n16) * WROW + k0 + quad * 8);
                acc[0][ot] = __builtin_amdgcn_mfma_f32_16x16x32_bf16(aw.s, bx0.s, acc[0][ot], 0, 0, 0);
                acc[1][ot] = __builtin_amdgcn_mfma_f32_16x16x32_bf16(aw.s, bx1.s, acc[1][ot], 0, 0, 0);
            }
        }
    }

#pragma unroll
    for (int g = 0; g < 2; ++g) {
        const int m = mrow + g * 16;
        const int s = m >> 3, b = m & 7;
#pragma unroll
        for (int ot = 0; ot < 4; ++ot) {
            int obase = o0 + ot * 16 + quad * 4;   // 4 consecutive o per lane
            if (obase >= NPROJ) continue;
            f32x4 bv = *(const f32x4*)(bias + obase);
            union { unsigned short sh[4]; u32x2 u; } pk;
            pk.sh[0] = f2bf(acc[g][ot].x + bv.x);
            pk.sh[1] = f2bf(acc[g][ot].y + bv.y);
            pk.sh[2] = f2bf(acc[g][ot].z + bv.z);
            pk.sh[3] = f2bf(acc[g][ot].w + bv.w);
            unsigned short* dst;
            if (obase < 256) {
                int h = obase >> 5, d = obase & 31;
                dst = Qb + (((size_t)(h * BATCH + b)) * S_LEN + s) * QD + d;
            } else if (obase < 512) {
                int o2 = obase - 256;
                int h = o2 >> 5, d = o2 & 31;
                dst = Kb + (((size_t)(h * BATCH + b)) * S_LEN + s) * QD + d;
            } else {
                int h = (obase - 512) >> 2;
                dst = Pb + (((size_t)(h * BATCH + b)) * S_LEN + s) * PD;
            }
            *(u32x2*)dst = pk.u;
        }
    }
}

// ---------------------------------------------------------------------------
// Kernel 2: scores^T via MFMA + Toeplitz pos-fold + mask + softmax + write.
// Grid (S/16, H*B). Block 256 = 4 waves; wave wv covers j in [wv*256, +256).
// C^T tile: lane holds row i = i0 + (lane&15), cols j0+quad*4+{0..3}.
// PE read directly from pre-paired global table (L2-resident; R6 confirmed
// LDS staging was not a cost either way).
// R7 change: __launch_bounds__(256,4) ISOLATED (R1's lb4 test was confounded
// by setprio, which hurts barrier-synced kernels per learn_hip m190, and by
// prep-merge). Budget at 128 VGPR: sc 64 + frags 12 + addr ~16 = 92 base,
// ~9 prefetch slots; 4th resident block raises total outstanding loads/CU
// and store/compute overlap. LDS 36.6 KB x 4 = 146 KB <= 160 OK.
// Store epilogue (R4/R5, confirmed): wave-private LDS transpose, chunk=128 j,
// each store instr = 2 x 512B contiguous; rotation phys=(logical+4*row)&127
// keeps both LDS phases at the 8-word/bank floor. Single-barrier softmax.
// ---------------------------------------------------------------------------
__global__ __launch_bounds__(256, 4) void attn_kernel(
    const unsigned short* __restrict__ Qb, const unsigned short* __restrict__ Kb,
    const unsigned short* __restrict__ Pb, const u32x4* __restrict__ PEp,
    const unsigned char* __restrict__ mask, float* __restrict__ out)
{
    __shared__ float tbuf[4 * 2048];    // 32 KB: per-wave 16 rows x 128 words
    __shared__ float madd[S_LEN];
    __shared__ float redm[4][16];
    __shared__ float reds[4][16];

    const int hb = blockIdx.y;
    const int h = hb >> 3, b = hb & 7;
    const int i0 = blockIdx.x * 16;
    const int tid = threadIdx.x;
    const int wv = tid >> 6, lane = tid & 63;
    const int n16 = lane & 15, quad = lane >> 4;

    for (int j = tid; j < S_LEN; j += 256)
        madd[j] = mask[b * S_LEN + j] ? -INFINITY : 0.0f;

    // B1: Q fragment (row i0+n16, k = quad*8..+7)
    U4 b1; b1.u = *(const u32x4*)(Qb + ((size_t)hb * S_LEN + i0 + n16) * QD + quad * 8);
    // P row -> sparse B-frags for the two pos MFMAs
    u32x2 p4 = *(const u32x2*)(Pb + ((size_t)hb * S_LEN + i0 + n16) * PD);
    U4 b2, b3;
    b2.u.x = (n16 == 2 * quad)     ? p4.x : 0u;
    b2.u.y = (n16 == 2 * quad)     ? p4.y : 0u;
    b2.u.z = (n16 == 2 * quad + 1) ? p4.x : 0u;
    b2.u.w = (n16 == 2 * quad + 1) ? p4.y : 0u;
    b3.u.x = (n16 == 2 * quad + 8) ? p4.x : 0u;
    b3.u.y = (n16 == 2 * quad + 8) ? p4.y : 0u;
    b3.u.z = (n16 == 2 * quad + 9) ? p4.x : 0u;
    b3.u.w = (n16 == 2 * quad + 9) ? p4.y : 0u;

    __syncthreads();   // madd ready

    f32x4 sc[16];
    const unsigned short* kbase =
        Kb + (size_t)hb * S_LEN * QD + (size_t)(wv * 256 + n16) * QD + quad * 8;
    // per-lane base into the pre-paired PE table (slots relative to i0)
    const u32x4* pebase = PEp + (size_t)h * LPOS + i0
                        + (1023 - wv * 256 - n16 + 2 * quad);

#pragma unroll
    for (int t = 0; t < 16; ++t) {
        U4 a1; a1.u = *(const u32x4*)(kbase + t * 16 * QD);
        U4 a2; a2.u = pebase[-t * 16];      // {PE4[w], PE4[w+1]}
        U4 a3; a3.u = pebase[-t * 16 + 8];
        f32x4 acc = {0.0f, 0.0f, 0.0f, 0.0f};
        acc = __builtin_amdgcn_mfma_f32_16x16x32_bf16(a3.s, b3.s, acc, 0, 0, 0);
        acc = __builtin_amdgcn_mfma_f32_16x16x32_bf16(a2.s, b2.s, acc, 0, 0, 0);
        acc = __builtin_amdgcn_mfma_f32_16x16x32_bf16(a1.s, b1.s, acc, 0, 0, 0);
        sc[t] = acc + *(const f32x4*)&madd[wv * 256 + t * 16 + quad * 4];
    }

    // --- single-barrier softmax ---
    float mxw = -INFINITY;
#pragma unroll
    for (int t = 0; t < 16; ++t)
        mxw = fmaxf(mxw, fmaxf(fmaxf(sc[t].x, sc[t].y), fmaxf(sc[t].z, sc[t].w)));
    mxw = fmaxf(mxw, __shfl_xor(mxw, 16));
    mxw = fmaxf(mxw, __shfl_xor(mxw, 32));

    float sum = 0.0f;
#pragma unroll
    for (int t = 0; t < 16; ++t) {
        sc[t].x = __expf(sc[t].x - mxw);
        sc[t].y = __expf(sc[t].y - mxw);
        sc[t].z = __expf(sc[t].z - mxw);
        sc[t].w = __expf(sc[t].w - mxw);
        sum += sc[t].x + sc[t].y + sc[t].z + sc[t].w;
    }
    sum += __shfl_xor(sum, 16);
    sum += __shfl_xor(sum, 32);
    if (quad == 0) { redm[wv][n16] = mxw; reds[wv][n16] = sum; }
    __syncthreads();

    const float m0_ = redm[0][n16], m1_ = redm[1][n16];
    const float m2_ = redm[2][n16], m3_ = redm[3][n16];
    const float m = fmaxf(fmaxf(m0_, m1_), fmaxf(m2_, m3_));
    const float tot = reds[0][n16] * __expf(m0_ - m)
                    + reds[1][n16] * __expf(m1_ - m)
                    + reds[2][n16] * __expf(m2_ - m)
                    + reds[3][n16] * __expf(m3_ - m);
    const float scale = __expf(mxw - m) / tot;

    // --- transposed store: chunk = 8 t's = 128 consecutive j ---
    // write: lane (n16,quad) puts sc[c*8+tl]*scale at row n16,
    //        logical word tl*16+quad*4, phys = (logical + 4*row) & 127.
    // read:  lane l covers row r = (l>>5)+2*ii, logical (l&31)*4
    //        -> each store instr = 2 rows x 512B contiguous.
    // tbuf is wave-private (8 KB each): no cross-wave ordering needed.
    float* wbuf = tbuf + wv * 2048;
    const int i_out_base = (int)((size_t)hb * S_LEN + i0);
#pragma unroll
    for (int c = 0; c < 2; ++c) {
#pragma unroll
        for (int tl = 0; tl < 8; ++tl) {
            f32x4 o4 = sc[c * 8 + tl] * scale;
            int phys = ((tl * 16 + quad * 4) + 4 * n16) & 127;
            *(f32x4*)&wbuf[n16 * 128 + phys] = o4;
        }
#pragma unroll
        for (int ii = 0; ii < 8; ++ii) {
            int r = (lane >> 5) + 2 * ii;
            int phys = (((lane & 31) * 4) + 4 * r) & 127;
            f32x4 v = *(const f32x4*)&wbuf[r * 128 + phys];
            float* dst = out + (size_t)(i_out_base + r) * S_LEN
                         + wv * 256 + c * 128 + (lane & 31) * 4;
            __builtin_nontemporal_store(v, (f32x4*)dst);
        }
    }
}

// ---------------------------------------------------------------------------
extern "C" void kernel_launch(void* const* d_in, const int* in_sizes, int n_in,
                              void* d_out, int out_size, void* d_ws, size_t ws_size,
                              hipStream_t stream) {
    (void)in_sizes; (void)n_in; (void)out_size; (void)ws_size;
    const float* x           = (const float*)d_in[0];
    const float* pos_emb     = (const float*)d_in[1];
    const unsigned char* msk = (const unsigned char*)d_in[2];
    const float* in_proj_w   = (const float*)d_in[3];
    const float* in_proj_b   = (const float*)d_in[4];
    const float* linear_posw = (const float*)d_in[5];
    float* out = (float*)d_out;

    char* p = (char*)d_ws;
    unsigned short* Qb  = (unsigned short*)p; p += (size_t)4 << 20;  // 4 MB
    unsigned short* Kb  = (unsigned short*)p; p += (size_t)4 << 20;  // 4 MB
    unsigned short* Pb  = (unsigned short*)p; p += 524288;           // 0.5 MB
    unsigned short* PEp = (unsigned short*)p; p += 262144 + 4096;    // paired PE
    unsigned short* Xb  = (unsigned short*)p; p += (size_t)8 << 20;  // 8 MB
    unsigned short* Wb  = (unsigned short*)p; p += 557056;           // ~0.53 MB

    prep_kernel<<<2440, 256, 0, stream>>>(x, in_proj_w, pos_emb, linear_posw, Xb, Wb, PEp);
    proj_kernel<<<dim3(64, 9), 256, 0, stream>>>(Xb, Wb, in_proj_b, Qb, Kb, Pb);
    attn_kernel<<<dim3(64, 64), 256, 0, stream>>>(Qb, Kb, Pb, (const u32x4*)PEp, msk, out);
}

// Round 8
// 320.066 us; speedup vs baseline: 1.0975x; 1.0975x over previous
//
#include <hip/hip_runtime.h>
#include <math.h>

#define S_LEN 1024
#define BATCH 8
#define NH 8
#define QD 32
#define PD 4
#define EMB 512
#define NPROJ 544
#define LPOS 2047  // 2*S-1

typedef __attribute__((ext_vector_type(8))) short short8;   // 8 bf16 = 4 VGPR
typedef __attribute__((ext_vector_type(4))) float f32x4;
typedef __attribute__((ext_vector_type(4))) unsigned int u32x4;
typedef __attribute__((ext_vector_type(2))) unsigned int u32x2;

union U4 { u32x4 u; short8 s; };

// fp32 -> bf16 round-to-nearest-even
static __device__ inline unsigned short f2bf(float f) {
    unsigned int u = __builtin_bit_cast(unsigned int, f);
    u += 0x7fffu + ((u >> 16) & 1u);
    return (unsigned short)(u >> 16);
}

// ---------------------------------------------------------------------------
// Kernel 0: convert X (4,194,304 f32) and W (278,528 f32) to bf16.
// 2 f32x4 per thread -> one 16B store each.
// ---------------------------------------------------------------------------
#define NXV 1048576   // X float4 count
#define NWV 69632     // W float4 count
__global__ __launch_bounds__(256) void convert_kernel(
    const float* __restrict__ X, const float* __restrict__ W,
    unsigned short* __restrict__ Xb, unsigned short* __restrict__ Wb)
{
    int idx = blockIdx.x * 256 + threadIdx.x;
    int i = idx * 2;   // NXV is even: a pair never straddles the X/W boundary
    const f32x4* src;
    unsigned short* dst;
    if (i < NXV)            { src = (const f32x4*)X; dst = Xb; }
    else if (i < NXV + NWV) { src = (const f32x4*)W; dst = Wb; i -= NXV; }
    else return;
    f32x4 v0 = src[i], v1 = src[i + 1];
    union { unsigned short s[8]; u32x4 u; } pk;
    pk.s[0] = f2bf(v0.x); pk.s[1] = f2bf(v0.y);
    pk.s[2] = f2bf(v0.z); pk.s[3] = f2bf(v0.w);
    pk.s[4] = f2bf(v1.x); pk.s[5] = f2bf(v1.y);
    pk.s[6] = f2bf(v1.z); pk.s[7] = f2bf(v1.w);
    ((u32x4*)dst)[i >> 1] = pk.u;
}

// ---------------------------------------------------------------------------
// Kernel 1: proj^T = W(544x512) @ X^T(512x8192) via MFMA.
// W o-tile staged in LDS (2 k-phases of 256), conflict-free padded rows.
// Block 256 (4 waves): tile 64 o x 128 m; wave wv: 32 m-rows (2 groups of 16),
// 4 o-subtiles -> 8 MFMAs per kk, each LDS aw read feeds 2 MFMAs.
// ---------------------------------------------------------------------------
#define WROW 264   // shorts per LDS W row (256 data + 8 pad): 528 B, 16B-aligned,
                   // row step 132 words -> +4 banks/row -> 2-way on b128 (free)
__global__ __launch_bounds__(256) void proj_kernel(
    const unsigned short* __restrict__ Xb, const unsigned short* __restrict__ Wb,
    const float* __restrict__ bias,
    unsigned short* __restrict__ Qb, unsigned short* __restrict__ Kb,
    unsigned short* __restrict__ Pb)
{
    __shared__ unsigned short wlds[64 * WROW];   // 33,792 B

    const int tid = threadIdx.x;
    const int wv = tid >> 6, lane = tid & 63;
    const int n16 = lane & 15, quad = lane >> 4;
    const int m0 = blockIdx.x * 128, o0 = blockIdx.y * 64;
    const int mrow = m0 + wv * 32 + n16;          // group g adds +16
    const unsigned short* xrow = Xb + (size_t)mrow * EMB;

    f32x4 acc[2][4] = {{{0,0,0,0},{0,0,0,0},{0,0,0,0},{0,0,0,0}},
                       {{0,0,0,0},{0,0,0,0},{0,0,0,0},{0,0,0,0}}};

#pragma unroll
    for (int phase = 0; phase < 2; ++phase) {
        __syncthreads();   // previous phase fully consumed
#pragma unroll
        for (int u = 0; u < 8; ++u) {
            int idx = tid + 256 * u;          // 0..2047
            int r = idx >> 5, c = idx & 31;   // row, 16B chunk within 512B half-row
            int o = o0 + r; if (o > NPROJ - 1) o = NPROJ - 1;
            u32x4 v = *(const u32x4*)(Wb + (size_t)o * EMB + phase * 256 + c * 8);
            *(u32x4*)(wlds + r * WROW + c * 8) = v;
        }
        __syncthreads();
#pragma unroll
        for (int kk = 0; kk < 8; ++kk) {
            const int k0 = kk * 32;
            U4 bx0; bx0.u = *(const u32x4*)(xrow + phase * 256 + k0 + quad * 8);
            U4 bx1; bx1.u = *(const u32x4*)(xrow + (size_t)16 * EMB + phase * 256 + k0 + quad * 8);
#pragma unroll
            for (int ot = 0; ot < 4; ++ot) {
                U4 aw; aw.u = *(const u32x4*)(wlds + (ot * 16 + n16) * WROW + k0 + quad * 8);
                acc[0][ot] = __builtin_amdgcn_mfma_f32_16x16x32_bf16(aw.s, bx0.s, acc[0][ot], 0, 0, 0);
                acc[1][ot] = __builtin_amdgcn_mfma_f32_16x16x32_bf16(aw.s, bx1.s, acc[1][ot], 0, 0, 0);
            }
        }
    }

#pragma unroll
    for (int g = 0; g < 2; ++g) {
        const int m = mrow + g * 16;
        const int s = m >> 3, b = m & 7;
#pragma unroll
        for (int ot = 0; ot < 4; ++ot) {
            int obase = o0 + ot * 16 + quad * 4;   // 4 consecutive o per lane
            if (obase >= NPROJ) continue;
            f32x4 bv = *(const f32x4*)(bias + obase);
            union { unsigned short sh[4]; u32x2 u; } pk;
            pk.sh[0] = f2bf(acc[g][ot].x + bv.x);
            pk.sh[1] = f2bf(acc[g][ot].y + bv.y);
            pk.sh[2] = f2bf(acc[g][ot].z + bv.z);
            pk.sh[3] = f2bf(acc[g][ot].w + bv.w);
            unsigned short* dst;
            if (obase < 256) {
                int h = obase >> 5, d = obase & 31;
                dst = Qb + (((size_t)(h * BATCH + b)) * S_LEN + s) * QD + d;
            } else if (obase < 512) {
                int o2 = obase - 256;
                int h = o2 >> 5, d = o2 & 31;
                dst = Kb + (((size_t)(h * BATCH + b)) * S_LEN + s) * QD + d;
            } else {
                int h = (obase - 512) >> 2;
                dst = Pb + (((size_t)(h * BATCH + b)) * S_LEN + s) * PD;
            }
            *(u32x2*)dst = pk.u;
        }
    }
}

// ---------------------------------------------------------------------------
// Kernel 2: PE[l][ht] = dot(pos[l], Wp[ht]); store reversed bf16 PAIRS:
// PEp[h][w] (16B) = { PE4r[h][w], PE4r[h][w+1] } where PE4r[h][w][t] =
// bf16(PE[2046-w][h*4+t]). Each computed value lands in the lo-half of
// slot w and the hi-half of slot w-1 (two u16 stores). Slot 2046's hi-half
// is never written and never read (attn reads slots <= 2045).
// ---------------------------------------------------------------------------
__global__ __launch_bounds__(256) void pe_kernel(
    const float* __restrict__ pos, const float* __restrict__ Wp,
    unsigned short* __restrict__ PEp)
{
    int o = blockIdx.x * 256 + threadIdx.x;
    if (o >= LPOS * 32) return;
    int l = o >> 5, ht = o & 31;
    const f32x4* pr = (const f32x4*)(pos + (size_t)l * 192);
    const f32x4* wr = (const f32x4*)(Wp + (size_t)ht * 192);
    float acc = 0.0f;
#pragma unroll 8
    for (int d = 0; d < 48; ++d) {
        f32x4 a = pr[d], w = wr[d];
        acc += a.x * w.x + a.y * w.y + a.z * w.z + a.w * w.w;
    }
    int h = ht >> 2, t = ht & 3, w = 2046 - l;
    unsigned short v = f2bf(acc);
    PEp[((size_t)h * LPOS + w) * 8 + t] = v;
    if (w >= 1)
        PEp[((size_t)h * LPOS + (w - 1)) * 8 + 4 + t] = v;
}

// ---------------------------------------------------------------------------
// Kernel 3: scores^T via MFMA + Toeplitz pos-fold + mask + softmax + write.
// Grid (S/16, H*B). Block 256 = 4 waves; wave wv covers j in [wv*256, +256).
// C^T tile: lane holds row i = i0 + (lane&15), cols j0+quad*4+{0..3}.
// PE read directly from pre-paired global table (L2-resident).
// SETTLED by A/B across R0-R7 (all vs the ~322 best):
//  - lb(256,3): lb(256,4) spills sc[16] through softmax/store -> +29us (R7).
//  - no setprio (R1), no multi-group amortization (R2, +8us),
//  - no PE LDS staging (R6, neutral; global gather is equal and simpler),
//  - wave-private LDS transpose store, chunk=128 j (R4: +25us vs scatter;
//    R5 chunk 64->128: +2us). Each store instr = 2 x 512B contiguous.
//    Rotation phys=(logical+4*row)&127 -> 8-word/bank floor on both phases.
//  - single-barrier softmax (wave-local exp pre-barrier, fold-up at store).
// ---------------------------------------------------------------------------
__global__ __launch_bounds__(256, 3) void attn_kernel(
    const unsigned short* __restrict__ Qb, const unsigned short* __restrict__ Kb,
    const unsigned short* __restrict__ Pb, const u32x4* __restrict__ PEp,
    const unsigned char* __restrict__ mask, float* __restrict__ out)
{
    __shared__ float tbuf[4 * 2048];    // 32 KB: per-wave 16 rows x 128 words
    __shared__ float madd[S_LEN];
    __shared__ float redm[4][16];
    __shared__ float reds[4][16];

    const int hb = blockIdx.y;
    const int h = hb >> 3, b = hb & 7;
    const int i0 = blockIdx.x * 16;
    const int tid = threadIdx.x;
    const int wv = tid >> 6, lane = tid & 63;
    const int n16 = lane & 15, quad = lane >> 4;

    for (int j = tid; j < S_LEN; j += 256)
        madd[j] = mask[b * S_LEN + j] ? -INFINITY : 0.0f;

    // B1: Q fragment (row i0+n16, k = quad*8..+7)
    U4 b1; b1.u = *(const u32x4*)(Qb + ((size_t)hb * S_LEN + i0 + n16) * QD + quad * 8);
    // P row -> sparse B-frags for the two pos MFMAs
    u32x2 p4 = *(const u32x2*)(Pb + ((size_t)hb * S_LEN + i0 + n16) * PD);
    U4 b2, b3;
    b2.u.x = (n16 == 2 * quad)     ? p4.x : 0u;
    b2.u.y = (n16 == 2 * quad)     ? p4.y : 0u;
    b2.u.z = (n16 == 2 * quad + 1) ? p4.x : 0u;
    b2.u.w = (n16 == 2 * quad + 1) ? p4.y : 0u;
    b3.u.x = (n16 == 2 * quad + 8) ? p4.x : 0u;
    b3.u.y = (n16 == 2 * quad + 8) ? p4.y : 0u;
    b3.u.z = (n16 == 2 * quad + 9) ? p4.x : 0u;
    b3.u.w = (n16 == 2 * quad + 9) ? p4.y : 0u;

    __syncthreads();   // madd ready

    f32x4 sc[16];
    const unsigned short* kbase =
        Kb + (size_t)hb * S_LEN * QD + (size_t)(wv * 256 + n16) * QD + quad * 8;
    // per-lane base into the pre-paired PE table (slots relative to i0)
    const u32x4* pebase = PEp + (size_t)h * LPOS + i0
                        + (1023 - wv * 256 - n16 + 2 * quad);

#pragma unroll
    for (int t = 0; t < 16; ++t) {
        U4 a1; a1.u = *(const u32x4*)(kbase + t * 16 * QD);
        U4 a2; a2.u = pebase[-t * 16];      // {PE4[w], PE4[w+1]}
        U4 a3; a3.u = pebase[-t * 16 + 8];
        f32x4 acc = {0.0f, 0.0f, 0.0f, 0.0f};
        acc = __builtin_amdgcn_mfma_f32_16x16x32_bf16(a3.s, b3.s, acc, 0, 0, 0);
        acc = __builtin_amdgcn_mfma_f32_16x16x32_bf16(a2.s, b2.s, acc, 0, 0, 0);
        acc = __builtin_amdgcn_mfma_f32_16x16x32_bf16(a1.s, b1.s, acc, 0, 0, 0);
        sc[t] = acc + *(const f32x4*)&madd[wv * 256 + t * 16 + quad * 4];
    }

    // --- single-barrier softmax ---
    float mxw = -INFINITY;
#pragma unroll
    for (int t = 0; t < 16; ++t)
        mxw = fmaxf(mxw, fmaxf(fmaxf(sc[t].x, sc[t].y), fmaxf(sc[t].z, sc[t].w)));
    mxw = fmaxf(mxw, __shfl_xor(mxw, 16));
    mxw = fmaxf(mxw, __shfl_xor(mxw, 32));

    float sum = 0.0f;
#pragma unroll
    for (int t = 0; t < 16; ++t) {
        sc[t].x = __expf(sc[t].x - mxw);
        sc[t].y = __expf(sc[t].y - mxw);
        sc[t].z = __expf(sc[t].z - mxw);
        sc[t].w = __expf(sc[t].w - mxw);
        sum += sc[t].x + sc[t].y + sc[t].z + sc[t].w;
    }
    sum += __shfl_xor(sum, 16);
    sum += __shfl_xor(sum, 32);
    if (quad == 0) { redm[wv][n16] = mxw; reds[wv][n16] = sum; }
    __syncthreads();

    const float m0_ = redm[0][n16], m1_ = redm[1][n16];
    const float m2_ = redm[2][n16], m3_ = redm[3][n16];
    const float m = fmaxf(fmaxf(m0_, m1_), fmaxf(m2_, m3_));
    const float tot = reds[0][n16] * __expf(m0_ - m)
                    + reds[1][n16] * __expf(m1_ - m)
                    + reds[2][n16] * __expf(m2_ - m)
                    + reds[3][n16] * __expf(m3_ - m);
    const float scale = __expf(mxw - m) / tot;

    // --- transposed store: chunk = 8 t's = 128 consecutive j ---
    // write: lane (n16,quad) puts sc[c*8+tl]*scale at row n16,
    //        logical word tl*16+quad*4, phys = (logical + 4*row) & 127.
    // read:  lane l covers row r = (l>>5)+2*ii, logical (l&31)*4
    //        -> each store instr = 2 rows x 512B contiguous.
    // tbuf is wave-private (8 KB each): no cross-wave ordering needed.
    float* wbuf = tbuf + wv * 2048;
    const int i_out_base = (int)((size_t)hb * S_LEN + i0);
#pragma unroll
    for (int c = 0; c < 2; ++c) {
#pragma unroll
        for (int tl = 0; tl < 8; ++tl) {
            f32x4 o4 = sc[c * 8 + tl] * scale;
            int phys = ((tl * 16 + quad * 4) + 4 * n16) & 127;
            *(f32x4*)&wbuf[n16 * 128 + phys] = o4;
        }
#pragma unroll
        for (int ii = 0; ii < 8; ++ii) {
            int r = (lane >> 5) + 2 * ii;
            int phys = (((lane & 31) * 4) + 4 * r) & 127;
            f32x4 v = *(const f32x4*)&wbuf[r * 128 + phys];
            float* dst = out + (size_t)(i_out_base + r) * S_LEN
                         + wv * 256 + c * 128 + (lane & 31) * 4;
            __builtin_nontemporal_store(v, (f32x4*)dst);
        }
    }
}

// ---------------------------------------------------------------------------
extern "C" void kernel_launch(void* const* d_in, const int* in_sizes, int n_in,
                              void* d_out, int out_size, void* d_ws, size_t ws_size,
                              hipStream_t stream) {
    (void)in_sizes; (void)n_in; (void)out_size; (void)ws_size;
    const float* x           = (const float*)d_in[0];
    const float* pos_emb     = (const float*)d_in[1];
    const unsigned char* msk = (const unsigned char*)d_in[2];
    const float* in_proj_w   = (const float*)d_in[3];
    const float* in_proj_b   = (const float*)d_in[4];
    const float* linear_posw = (const float*)d_in[5];
    float* out = (float*)d_out;

    char* p = (char*)d_ws;
    unsigned short* Qb  = (unsigned short*)p; p += (size_t)4 << 20;  // 4 MB
    unsigned short* Kb  = (unsigned short*)p; p += (size_t)4 << 20;  // 4 MB
    unsigned short* Pb  = (unsigned short*)p; p += 524288;           // 0.5 MB
    unsigned short* PEp = (unsigned short*)p; p += 262144 + 4096;    // paired PE
    unsigned short* Xb  = (unsigned short*)p; p += (size_t)8 << 20;  // 8 MB
    unsigned short* Wb  = (unsigned short*)p; p += 557056;           // ~0.53 MB

    convert_kernel<<<2184, 256, 0, stream>>>(x, in_proj_w, Xb, Wb);
    pe_kernel<<<256, 256, 0, stream>>>(pos_emb, linear_posw, PEp);
    proj_kernel<<<dim3(64, 9), 256, 0, stream>>>(Xb, Wb, in_proj_b, Qb, Kb, Pb);
    attn_kernel<<<dim3(64, 64), 256, 0, stream>>>(Qb, Kb, Pb, (const u32x4*)PEp, msk, out);
}